// Round 12
// baseline (222.165 us; speedup 1.0000x reference)
//
#include <hip/hip_runtime.h>
#include <math.h>

// SelfAttentionLayer B=4, N=2048, D=E=1024, fp32 in/out.
// out[b,j,e] = sum_i softmax_i(q_i . k_j / 32) * v[b,i,e]
// R16: (1) pv -> 128x128 tiles / 256 threads / 64KB LDS -> 2 blocks/CU,
//      grid 512 exact (attacks the barrier-stall half of the LDS-BW model:
//      measured MfmaUtil 31% vs ~60% LDS ceiling at 1 block/CU).
//      (2) merge qk+v into one kernel (independent; saves a boundary).
//      scores/prep unchanged from R15 (passed, 217.2us).
//
// ws (ushort): xb[8M] Wqkvt[3M] QKb[16M] Vtb[8M] Pb[16M] l[8192 f32].

typedef __bf16 bf16x8 __attribute__((ext_vector_type(8)));
typedef float f32x4 __attribute__((ext_vector_type(4)));

static __device__ __forceinline__ unsigned short f2bf(float f) {
    unsigned u = __float_as_uint(f);
    u += 0x7fff + ((u >> 16) & 1);   // round-to-nearest-even
    return (unsigned short)(u >> 16);
}

#define GLDS16(gptr, lptr)                                                            \
    __builtin_amdgcn_global_load_lds(                                                 \
        (const __attribute__((address_space(1))) void*)(gptr),                        \
        (__attribute__((address_space(3))) void*)(lptr), 16, 0, 0)

#define BARSYNC  __builtin_amdgcn_s_barrier()
#define WAITLGKM do { asm volatile("s_waitcnt lgkmcnt(0)" ::: "memory");    \
                      __builtin_amdgcn_sched_barrier(0); } while (0)

// ===================== 256x256 8-phase GEMM core =====================
// (R11-R15 structure, proven: conflicts 0, passed refcheck 5x.)
__device__ __forceinline__ void gemm256_core(
    const unsigned short* __restrict__ Ab,   // + gm0*ld
    const unsigned short* __restrict__ Bb,   // + gn0*ld
    const long ld, unsigned short* lds, f32x4 acc[8][4])
{
    const int tid  = threadIdx.x;
    const int w    = tid >> 6;
    const int lane = tid & 63;

    const int r  = lane >> 3;
    const int s  = lane & 7;
    const int cg = (s ^ r) * 8;

    const int fr    = lane & 15;
    const int quad  = lane >> 4;
    const int sw    = fr & 7;
    const int arow0 = (w >> 2) * 128;
    const int brow0 = (w & 3) * 64;

#define STG_A(t, mh, buf) do {                                              \
    const int rb_ = (w >> 2) * 128 + (mh) * 64 + (w & 3) * 16;              \
    const unsigned short* g_ = Ab + (long)(rb_ + r) * ld + (long)(t) * 64 + cg; \
    unsigned short* d_ = lds + (buf) * 16384 + rb_ * 64;                    \
    GLDS16(g_, d_); GLDS16(g_ + 8 * ld, d_ + 512); } while (0)
#define STG_B(t, nh, buf) do {                                              \
    const int rb_ = (w >> 1) * 64 + (nh) * 32 + (w & 1) * 16;               \
    const unsigned short* g_ = Bb + (long)(rb_ + r) * ld + (long)(t) * 64 + cg; \
    unsigned short* d_ = lds + 32768 + (buf) * 16384 + rb_ * 64;            \
    GLDS16(g_, d_); GLDS16(g_ + 8 * ld, d_ + 512); } while (0)

    bf16x8 af[4][2], bfA[2][2], bfB[2][2];
#define LOADA(buf, mh) do {                                                 \
    _Pragma("unroll") for (int ks_ = 0; ks_ < 2; ks_++)                     \
    _Pragma("unroll") for (int i_ = 0; i_ < 4; i_++)                        \
        af[i_][ks_] = *(const bf16x8*)&lds[(buf) * 16384 +                  \
            (arow0 + (mh) * 64 + i_ * 16 + fr) * 64 +                       \
            ((ks_ * 4 + quad) ^ sw) * 8]; } while (0)
#define LOADB(BF, buf, nh) do {                                             \
    _Pragma("unroll") for (int ks_ = 0; ks_ < 2; ks_++)                     \
    _Pragma("unroll") for (int j_ = 0; j_ < 2; j_++)                        \
        BF[j_][ks_] = *(const bf16x8*)&lds[32768 + (buf) * 16384 +          \
            (brow0 + (nh) * 32 + j_ * 16 + fr) * 64 +                       \
            ((ks_ * 4 + quad) ^ sw) * 8]; } while (0)

#define MFMA16(mh, nh, BF) do {                                             \
    __builtin_amdgcn_s_setprio(1);                                          \
    _Pragma("unroll") for (int ks_ = 0; ks_ < 2; ks_++)                     \
    _Pragma("unroll") for (int i_ = 0; i_ < 4; i_++)                        \
    _Pragma("unroll") for (int j_ = 0; j_ < 2; j_++)                        \
        acc[(mh) * 4 + i_][(nh) * 2 + j_] =                                 \
            __builtin_amdgcn_mfma_f32_16x16x32_bf16(                        \
                af[i_][ks_], BF[j_][ks_],                                   \
                acc[(mh) * 4 + i_][(nh) * 2 + j_], 0, 0, 0);                \
    __builtin_amdgcn_s_setprio(0); } while (0)

#pragma unroll
    for (int i = 0; i < 8; i++)
#pragma unroll
        for (int j = 0; j < 4; j++) acc[i][j] = f32x4{0.f, 0.f, 0.f, 0.f};

    // prologue: buf0 <- tile0 (4 units); buf1 <- tile1 partial (mh0, nh1)
    STG_A(0, 0, 0); STG_A(0, 1, 0); STG_B(0, 0, 0); STG_B(0, 1, 0);
    STG_A(1, 0, 1); STG_B(1, 1, 1);
    asm volatile("s_waitcnt vmcnt(4)" ::: "memory");   // buf0 complete
    BARSYNC;

#pragma unroll 1
    for (int i = 0; i < 8; ++i) {
        const int t1 = 2 * i + 1;
        const int t2 = (2 * i + 2) & 15;   // dummy re-read on last iter (safe)
        const int t3 = (2 * i + 3) & 15;
        // ph1 (buf0, mh0, nh0)
        LOADA(0, 0); LOADB(bfA, 0, 0); STG_B(t1, 0, 1);
        BARSYNC; WAITLGKM; MFMA16(0, 0, bfA); BARSYNC;
        // ph2 (buf0, mh0, nh1)
        LOADB(bfB, 0, 1); STG_A(t1, 1, 1);
        BARSYNC; WAITLGKM; MFMA16(0, 1, bfB); BARSYNC;
        // ph3 (buf0, mh1, nh1)
        LOADA(0, 1); STG_A(t2, 0, 0);
        BARSYNC; WAITLGKM; MFMA16(1, 1, bfB); BARSYNC;
        // ph4 (buf0, mh1, nh0) reuses bfA + drain: buf1 <- t1 complete
        STG_B(t2, 1, 0);
        BARSYNC; MFMA16(1, 0, bfA);
        asm volatile("s_waitcnt vmcnt(4)" ::: "memory"); BARSYNC;
        // ph5 (buf1, mh0, nh0)
        LOADA(1, 0); LOADB(bfA, 1, 0); STG_A(t2, 1, 0);
        BARSYNC; WAITLGKM; MFMA16(0, 0, bfA); BARSYNC;
        // ph6 (buf1, mh0, nh1)
        LOADB(bfB, 1, 1); STG_B(t2, 0, 0);
        BARSYNC; WAITLGKM; MFMA16(0, 1, bfB); BARSYNC;
        // ph7 (buf1, mh1, nh1)
        LOADA(1, 1); STG_A(t3, 0, 1);
        BARSYNC; WAITLGKM; MFMA16(1, 1, bfB); BARSYNC;
        // ph8 (buf1, mh1, nh0) reuses bfA + drain: buf0 <- t2 complete
        STG_B(t3, 1, 1);
        BARSYNC; MFMA16(1, 0, bfA);
        asm volatile("s_waitcnt vmcnt(4)" ::: "memory"); BARSYNC;
    }
    asm volatile("s_waitcnt vmcnt(0)" ::: "memory");   // drain dummy stages

#undef STG_A
#undef STG_B
#undef LOADA
#undef LOADB
#undef MFMA16
}

// ===================== 128x256 8-phase V core =====================
// (R14/R15 structure, passed refcheck.) 512 threads, LDS 96KB.
__device__ __forceinline__ void gemm_v128_core(
    const unsigned short* __restrict__ Ab,   // xb + gm0*1024
    const unsigned short* __restrict__ Bb,   // Wvt + gn0*1024
    unsigned short* lds, f32x4 acc[4][4])
{
    const int tid  = threadIdx.x;
    const int w    = tid >> 6;
    const int lane = tid & 63;

    const int r  = lane >> 3;
    const int s  = lane & 7;
    const int cg = (s ^ r) * 8;

    const int fr    = lane & 15;
    const int quad  = lane >> 4;
    const int sw    = fr & 7;
    const int arow0 = (w >> 2) * 64;
    const int brow0 = (w & 3) * 64;

#define STG_VA(t, mh, buf) do {                                             \
    const int rb_ = (w >> 2) * 64 + (mh) * 32 + (w & 3) * 8;                \
    const unsigned short* g_ = Ab + (long)(rb_ + r) * 1024 + (long)(t) * 64 + cg; \
    unsigned short* d_ = lds + (buf) * 8192 + rb_ * 64;                     \
    GLDS16(g_, d_); } while (0)
#define STG_VB(t, nh, buf) do {                                             \
    const int rb_ = (w >> 1) * 64 + (nh) * 32 + (w & 1) * 16;               \
    const unsigned short* g_ = Bb + (long)(rb_ + r) * 1024 + (long)(t) * 64 + cg; \
    unsigned short* d_ = lds + 16384 + (buf) * 16384 + rb_ * 64;            \
    GLDS16(g_, d_); GLDS16(g_ + 8 * 1024, d_ + 512); } while (0)

    bf16x8 af[2][2], bfA[2][2], bfB[2][2];
#define LOADVA(buf, mh) do {                                                \
    _Pragma("unroll") for (int ks_ = 0; ks_ < 2; ks_++)                     \
    _Pragma("unroll") for (int i_ = 0; i_ < 2; i_++)                        \
        af[i_][ks_] = *(const bf16x8*)&lds[(buf) * 8192 +                   \
            (arow0 + (mh) * 32 + i_ * 16 + fr) * 64 +                       \
            ((ks_ * 4 + quad) ^ sw) * 8]; } while (0)
#define LOADVB(BF, buf, nh) do {                                            \
    _Pragma("unroll") for (int ks_ = 0; ks_ < 2; ks_++)                     \
    _Pragma("unroll") for (int j_ = 0; j_ < 2; j_++)                        \
        BF[j_][ks_] = *(const bf16x8*)&lds[16384 + (buf) * 16384 +          \
            (brow0 + (nh) * 32 + j_ * 16 + fr) * 64 +                       \
            ((ks_ * 4 + quad) ^ sw) * 8]; } while (0)

#define MFMA_V(mh, nh, BF) do {                                             \
    __builtin_amdgcn_s_setprio(1);                                          \
    _Pragma("unroll") for (int ks_ = 0; ks_ < 2; ks_++)                     \
    _Pragma("unroll") for (int i_ = 0; i_ < 2; i_++)                        \
    _Pragma("unroll") for (int j_ = 0; j_ < 2; j_++)                        \
        acc[(mh) * 2 + i_][(nh) * 2 + j_] =                                 \
            __builtin_amdgcn_mfma_f32_16x16x32_bf16(                        \
                af[i_][ks_], BF[j_][ks_],                                   \
                acc[(mh) * 2 + i_][(nh) * 2 + j_], 0, 0, 0);                \
    __builtin_amdgcn_s_setprio(0); } while (0)

#pragma unroll
    for (int i = 0; i < 4; i++)
#pragma unroll
        for (int j = 0; j < 4; j++) acc[i][j] = f32x4{0.f, 0.f, 0.f, 0.f};

    // prologue: buf0 <- tile0 (6 loads); buf1 <- tile1 partial (A-mh0 1, B-nh1 2)
    STG_VA(0, 0, 0); STG_VA(0, 1, 0); STG_VB(0, 0, 0); STG_VB(0, 1, 0);
    STG_VA(1, 0, 1); STG_VB(1, 1, 1);
    asm volatile("s_waitcnt vmcnt(3)" ::: "memory");   // buf0 complete
    BARSYNC;

#pragma unroll 1
    for (int i = 0; i < 8; ++i) {
        const int t1 = 2 * i + 1;
        const int t2 = (2 * i + 2) & 15;   // dummy re-read on last iter (safe)
        const int t3 = (2 * i + 3) & 15;
        // ph1 (buf0, mh0, nh0)
        LOADVA(0, 0); LOADVB(bfA, 0, 0); STG_VB(t1, 0, 1);
        BARSYNC; WAITLGKM; MFMA_V(0, 0, bfA); BARSYNC;
        // ph2 (buf0, mh0, nh1)
        LOADVB(bfB, 0, 1); STG_VA(t1, 1, 1);
        BARSYNC; WAITLGKM; MFMA_V(0, 1, bfB); BARSYNC;
        // ph3 (buf0, mh1, nh1)
        LOADVA(0, 1); STG_VA(t2, 0, 0);
        BARSYNC; WAITLGKM; MFMA_V(1, 1, bfB); BARSYNC;
        // ph4 (buf0, mh1, nh0) reuses bfA + drain: buf1 <- t1 complete
        STG_VB(t2, 1, 0);
        BARSYNC; MFMA_V(1, 0, bfA);
        asm volatile("s_waitcnt vmcnt(3)" ::: "memory"); BARSYNC;
        // ph5 (buf1, mh0, nh0)
        LOADVA(1, 0); LOADVB(bfA, 1, 0); STG_VA(t2, 1, 0);
        BARSYNC; WAITLGKM; MFMA_V(0, 0, bfA); BARSYNC;
        // ph6 (buf1, mh0, nh1)
        LOADVB(bfB, 1, 1); STG_VB(t2, 0, 0);
        BARSYNC; WAITLGKM; MFMA_V(0, 1, bfB); BARSYNC;
        // ph7 (buf1, mh1, nh1)
        LOADVA(1, 1); STG_VA(t3, 0, 1);
        BARSYNC; WAITLGKM; MFMA_V(1, 1, bfB); BARSYNC;
        // ph8 (buf1, mh1, nh0) reuses bfA + drain: buf0 <- t2 complete
        STG_VB(t3, 1, 1);
        BARSYNC; MFMA_V(1, 0, bfA);
        asm volatile("s_waitcnt vmcnt(3)" ::: "memory"); BARSYNC;
    }
    asm volatile("s_waitcnt vmcnt(0)" ::: "memory");   // drain dummy stages

#undef STG_VA
#undef STG_VB
#undef LOADVA
#undef LOADVB
#undef MFMA_V
}

// ===================== 128x128 8-phase PV core (256 threads) ==========
// NEW R16. A = P rows (lda 2048), B = Vt rows (ldb 8192). K = 2048.
// LDS 64KB: A[buf][128][64] at buf*8192; B[buf][128][64] at 16384+buf*8192.
// 4 waves (2Mj x 2Ne): per-wave 64x64, acc[4][4]. 2 blocks/CU.
// Stage units (8KB, 2 GLDS/thread), matching read-sets exactly:
//   A(mh): rows {0,64}+mh*32..+31 ; rb_=(w>>1)*64+mh*32+(w&1)*16
//   B(nh): rows {0,64}+nh*32..+31 ; rb_=(w&1)*64+nh*32+(w>>1)*16
// Reads/phase 8/4/4/0; MFMA 8/phase. Same window schedule as 256-core
// (1 stage-unit per phase, identical in-flight counts) -> vmcnt(4) at
// ph4/ph8; prologue 6 units, vmcnt(4) drain.
__device__ __forceinline__ void pv128_core(
    const unsigned short* __restrict__ Ab,   // P + bz*4M + gm0*2048
    const unsigned short* __restrict__ Bb,   // Vt + gn0*8192 + bz*2048
    unsigned short* lds, f32x4 acc[4][4])
{
    const int tid  = threadIdx.x;
    const int w    = tid >> 6;        // 0..3
    const int lane = tid & 63;

    const int r  = lane >> 3;
    const int s  = lane & 7;
    const int cg = (s ^ r) * 8;

    const int fr    = lane & 15;
    const int quad  = lane >> 4;
    const int sw    = fr & 7;
    const int arow0 = (w >> 1) * 64;   // j wave-group
    const int brow0 = (w & 1) * 64;    // e wave-group

#define STG_QA(t, mh, buf) do {                                             \
    const int rb_ = (w >> 1) * 64 + (mh) * 32 + (w & 1) * 16;               \
    const unsigned short* g_ = Ab + (long)(rb_ + r) * 2048 + (long)(t) * 64 + cg; \
    unsigned short* d_ = lds + (buf) * 8192 + rb_ * 64;                     \
    GLDS16(g_, d_); GLDS16(g_ + 8 * 2048, d_ + 512); } while (0)
#define STG_QB(t, nh, buf) do {                                             \
    const int rb_ = (w & 1) * 64 + (nh) * 32 + (w >> 1) * 16;               \
    const unsigned short* g_ = Bb + (long)(rb_ + r) * 8192 + (long)(t) * 64 + cg; \
    unsigned short* d_ = lds + 16384 + (buf) * 8192 + rb_ * 64;             \
    GLDS16(g_, d_); GLDS16(g_ + 8 * 8192, d_ + 512); } while (0)

    bf16x8 af[2][2], bfA[2][2], bfB[2][2];
#define LOADQA(buf, mh) do {                                                \
    _Pragma("unroll") for (int ks_ = 0; ks_ < 2; ks_++)                     \
    _Pragma("unroll") for (int i_ = 0; i_ < 2; i_++)                        \
        af[i_][ks_] = *(const bf16x8*)&lds[(buf) * 8192 +                   \
            (arow0 + (mh) * 32 + i_ * 16 + fr) * 64 +                       \
            ((ks_ * 4 + quad) ^ sw) * 8]; } while (0)
#define LOADQB(BF, buf, nh) do {                                            \
    _Pragma("unroll") for (int ks_ = 0; ks_ < 2; ks_++)                     \
    _Pragma("unroll") for (int j_ = 0; j_ < 2; j_++)                        \
        BF[j_][ks_] = *(const bf16x8*)&lds[16384 + (buf) * 8192 +           \
            (brow0 + (nh) * 32 + j_ * 16 + fr) * 64 +                       \
            ((ks_ * 4 + quad) ^ sw) * 8]; } while (0)

#define MFMA_Q(mh, nh, BF) do {                                             \
    __builtin_amdgcn_s_setprio(1);                                          \
    _Pragma("unroll") for (int ks_ = 0; ks_ < 2; ks_++)                     \
    _Pragma("unroll") for (int i_ = 0; i_ < 2; i_++)                        \
    _Pragma("unroll") for (int j_ = 0; j_ < 2; j_++)                        \
        acc[(mh) * 2 + i_][(nh) * 2 + j_] =                                 \
            __builtin_amdgcn_mfma_f32_16x16x32_bf16(                        \
                af[i_][ks_], BF[j_][ks_],                                   \
                acc[(mh) * 2 + i_][(nh) * 2 + j_], 0, 0, 0);                \
    __builtin_amdgcn_s_setprio(0); } while (0)

#pragma unroll
    for (int i = 0; i < 4; i++)
#pragma unroll
        for (int j = 0; j < 4; j++) acc[i][j] = f32x4{0.f, 0.f, 0.f, 0.f};

    // prologue: buf0 <- tile0 (4 units); buf1 <- tile1 partial (A-mh0, B-nh1)
    STG_QA(0, 0, 0); STG_QA(0, 1, 0); STG_QB(0, 0, 0); STG_QB(0, 1, 0);
    STG_QA(1, 0, 1); STG_QB(1, 1, 1);
    asm volatile("s_waitcnt vmcnt(4)" ::: "memory");   // buf0 complete
    BARSYNC;

#pragma unroll 1
    for (int i = 0; i < 16; ++i) {
        const int t1 = 2 * i + 1;
        const int t2 = (2 * i + 2) & 31;   // dummy re-read on last iter (safe)
        const int t3 = (2 * i + 3) & 31;
        // ph1 (buf0, mh0, nh0)
        LOADQA(0, 0); LOADQB(bfA, 0, 0); STG_QB(t1, 0, 1);
        BARSYNC; WAITLGKM; MFMA_Q(0, 0, bfA); BARSYNC;
        // ph2 (buf0, mh0, nh1)
        LOADQB(bfB, 0, 1); STG_QA(t1, 1, 1);
        BARSYNC; WAITLGKM; MFMA_Q(0, 1, bfB); BARSYNC;
        // ph3 (buf0, mh1, nh1)
        LOADQA(0, 1); STG_QA(t2, 0, 0);
        BARSYNC; WAITLGKM; MFMA_Q(1, 1, bfB); BARSYNC;
        // ph4 (buf0, mh1, nh0) reuses bfA + drain: buf1 <- t1 complete
        STG_QB(t2, 1, 0);
        BARSYNC; MFMA_Q(1, 0, bfA);
        asm volatile("s_waitcnt vmcnt(4)" ::: "memory"); BARSYNC;
        // ph5 (buf1, mh0, nh0)
        LOADQA(1, 0); LOADQB(bfA, 1, 0); STG_QA(t2, 1, 0);
        BARSYNC; WAITLGKM; MFMA_Q(0, 0, bfA); BARSYNC;
        // ph6 (buf1, mh0, nh1)
        LOADQB(bfB, 1, 1); STG_QB(t2, 0, 0);
        BARSYNC; WAITLGKM; MFMA_Q(0, 1, bfB); BARSYNC;
        // ph7 (buf1, mh1, nh1)
        LOADQA(1, 1); STG_QA(t3, 0, 1);
        BARSYNC; WAITLGKM; MFMA_Q(1, 1, bfB); BARSYNC;
        // ph8 (buf1, mh1, nh0) reuses bfA + drain: buf0 <- t2 complete
        STG_QB(t3, 1, 1);
        BARSYNC; MFMA_Q(1, 0, bfA);
        asm volatile("s_waitcnt vmcnt(4)" ::: "memory"); BARSYNC;
    }
    asm volatile("s_waitcnt vmcnt(0)" ::: "memory");   // drain dummy stages

#undef STG_QA
#undef STG_QB
#undef LOADQA
#undef LOADQB
#undef MFMA_Q
}

// ---------------- merged Q/K + V GEMM (512 blocks) -------------------------
// blocks 0-255: qk (swapped: A=W rows f, B=x rows m; ushort4 -> QK[m][f]).
// blocks 256-511: v (Vt[e*8192+m]). Independent ops; v blocks may start
// as soon as CUs free (no dependency).
__global__ __launch_bounds__(512, 2) void gemm_qkv_split(
    const unsigned short* __restrict__ X, const unsigned short* __restrict__ W,
    unsigned short* __restrict__ QK, unsigned short* __restrict__ Vt)
{
    __shared__ unsigned short lds[65536];
    const int tid = threadIdx.x;
    const int w = tid >> 6, lane = tid & 63;
    const int fr = lane & 15, quad = lane >> 4;

    if (blockIdx.x < 256) {
        const int orig = blockIdx.x;
        const int xcd  = orig & 7;
        const int pos  = orig >> 3;           // 0..31
        const long gm0 = (long)(pos >> 2) * 256;            // feature f
        const long gn0 = (long)(xcd * 4 + (pos & 3)) * 256; // token m

        f32x4 acc[8][4];
        gemm256_core(W + gm0 * 1024, X + gn0 * 1024, 1024, lds, acc);

        const int wm = (w >> 2) * 128, wn = (w & 3) * 64;
#pragma unroll
        for (int mi = 0; mi < 8; mi++) {
            const long rb = gm0 + wm + (mi >> 2) * 64 + (mi & 3) * 16 + quad * 4;  // f
#pragma unroll
            for (int n = 0; n < 4; n++) {
                const long cb = gn0 + wn + n * 16 + fr;                            // m
                ushort4 o;
                o.x = f2bf(acc[mi][n][0]);
                o.y = f2bf(acc[mi][n][1]);
                o.z = f2bf(acc[mi][n][2]);
                o.w = f2bf(acc[mi][n][3]);
                *(ushort4*)&QK[cb * 2048L + rb] = o;
            }
        }
    } else {
        const int orig = blockIdx.x - 256;
        const int xcd  = orig & 7;
        const int pos  = orig >> 3;           // 0..31
        const long gm0 = (long)(xcd * 8 + (pos & 7)) * 128;
        const long gn0 = (long)(pos >> 3) * 256;

        f32x4 acc[4][4];
        gemm_v128_core(X + gm0 * 1024, W + 2 * 1024 * 1024L + gn0 * 1024, lds, acc);

        const int wm = (w >> 2) * 64, wn = (w & 3) * 64;
#pragma unroll
        for (int ai = 0; ai < 4; ai++) {
            const long rb = gm0 + wm + ai * 16 + quad * 4;
#pragma unroll
            for (int aj = 0; aj < 4; aj++) {
                const long ce = gn0 + wn + aj * 16 + fr;
                ushort4 o;
                o.x = f2bf(acc[ai][aj][0]);
                o.y = f2bf(acc[ai][aj][1]);
                o.z = f2bf(acc[ai][aj][2]);
                o.w = f2bf(acc[ai][aj][3]);
                *(ushort4*)&Vt[ce * 8192L + rb] = o;
            }
        }
    }
}

// ------------- scores GEMM (swapped: A=Q rows i, B=K rows j) ---------------
// (R15, passed.) C[i,j]; ushort4 -> P[j*2048+i]; lane-local l[j] sums.
__global__ __launch_bounds__(512, 2) void gemm_scores256(
    const unsigned short* __restrict__ QKb, unsigned short* __restrict__ P,
    float* __restrict__ l)
{
    __shared__ unsigned short lds[65536];
    const int orig = blockIdx.x;
    const int xcd  = orig & 7;
    const int pos  = orig >> 3;           // 0..31
    const int bz   = xcd >> 1;
    const long gm0 = (long)((xcd & 1) * 4 + (pos >> 3)) * 256;  // i (Q rows)
    const long gn0 = (long)(pos & 7) * 256;                     // j (K rows)

    const unsigned short* Ab = QKb + (long)bz * 2048 * 2048 + gm0 * 2048;         // Q
    const unsigned short* Bb = QKb + (long)bz * 2048 * 2048 + 1024 + gn0 * 2048;  // K

    f32x4 acc[8][4];
    gemm256_core(Ab, Bb, 2048, lds, acc);

    const int tid = threadIdx.x;
    const int w = tid >> 6, lane = tid & 63;
    const int fr = lane & 15, quad = lane >> 4;
    const int wm = (w >> 2) * 128, wn = (w & 3) * 64;

    unsigned short* Pb = P + (long)bz * 2048 * 2048;
    float* lb = l + (long)bz * 2048;
    const float scale = 1.0f / 32.0f;

    float colsum[4] = {0.f, 0.f, 0.f, 0.f};
#pragma unroll
    for (int mi = 0; mi < 8; mi++) {
        const long rb = gm0 + wm + (mi >> 2) * 64 + (mi & 3) * 16 + quad * 4;  // i
#pragma unroll
        for (int n = 0; n < 4; n++) {
            const long cb = gn0 + wn + n * 16 + fr;                            // j
            float e0 = __expf(acc[mi][n][0] * scale);
            float e1 = __expf(acc[mi][n][1] * scale);
            float e2 = __expf(acc[mi][n][2] * scale);
            float e3 = __expf(acc[mi][n][3] * scale);
            colsum[n] += (e0 + e1) + (e2 + e3);
            ushort4 o;
            o.x = f2bf(e0); o.y = f2bf(e1); o.z = f2bf(e2); o.w = f2bf(e3);
            *(ushort4*)&Pb[cb * 2048L + rb] = o;
        }
    }
    // combine the 4 quads (same j across quads), then one atomic per (w, fr, n)
#pragma unroll
    for (int n = 0; n < 4; n++) {
        colsum[n] += __shfl_xor(colsum[n], 16);
        colsum[n] += __shfl_xor(colsum[n], 32);
    }
    if (quad == 0) {
#pragma unroll
        for (int n = 0; n < 4; n++)
            atomicAdd(&lb[gn0 + wn + n * 16 + fr], colsum[n]);
    }
}

// ---------------- PV GEMM (128x128, 256 threads, 2 blocks/CU) -------------
// out_b[j,e] = (sum_i P'_b[j,i] * Vt[e, b*2048+i]) / l[b][j]
// Grid 512 = exact 1 round at 2 blocks/CU. XCD swizzle: bz = xcd>>1.
__global__ __launch_bounds__(256, 2) void gemm_pv128(
    const unsigned short* __restrict__ P, const unsigned short* __restrict__ Vt,
    const float* __restrict__ l, float* __restrict__ out)
{
    __shared__ unsigned short lds[32768];   // 64 KB
    const int orig = blockIdx.x;
    const int xcd  = orig & 7;
    const int pos  = orig >> 3;           // 0..63
    const int bz   = xcd >> 1;
    const long gm0 = (long)((xcd & 1) * 8 + (pos >> 3)) * 128;  // j (0..15)
    const long gn0 = (long)(pos & 7) * 128;                     // e (0..7)

    const unsigned short* Ab = P + (long)bz * 2048 * 2048 + gm0 * 2048;
    const unsigned short* Bb = Vt + gn0 * 8192 + (long)bz * 2048;

    f32x4 acc[4][4];
    pv128_core(Ab, Bb, lds, acc);

    const int tid = threadIdx.x;
    const int w = tid >> 6, lane = tid & 63;
    const int fr = lane & 15, quad = lane >> 4;
    const int wm = (w >> 1) * 64, wn = (w & 1) * 64;

    float* Ob = out + (long)bz * 2048 * 1024;
    const float* lb = l + (long)bz * 2048;
#pragma unroll
    for (int ai = 0; ai < 4; ai++) {
        const long rb = gm0 + wm + ai * 16 + quad * 4;
        float inv[4];
#pragma unroll
        for (int rr = 0; rr < 4; rr++) inv[rr] = 1.0f / lb[rb + rr];
#pragma unroll
        for (int aj = 0; aj < 4; aj++) {
            const long cb = gn0 + wn + aj * 16 + fr;
#pragma unroll
            for (int rr = 0; rr < 4; rr++)
                Ob[(rb + rr) * 1024L + cb] = acc[ai][aj][rr] * inv[rr];
        }
    }
}

// Fused prep: [0,8192) convert x; [8192,8192+3072) transpose weights;
// block 11264 zeroes l (8192 floats).
__global__ __launch_bounds__(256) void prep(
    const float* __restrict__ x,
    const float* __restrict__ Wq, const float* __restrict__ Wk,
    const float* __restrict__ Wv,
    unsigned short* __restrict__ xb, unsigned short* __restrict__ Wqkvt,
    float* __restrict__ l)
{
    __shared__ float t[32][33];
    const int b = blockIdx.x;
    const int tid = threadIdx.x;
    if (b < 8192) {
        int i = b * 256 + tid;
        float4 v = ((const float4*)x)[i];
        ushort4 o;
        o.x = f2bf(v.x); o.y = f2bf(v.y); o.z = f2bf(v.z); o.w = f2bf(v.w);
        ((ushort4*)xb)[i] = o;
        return;
    }
    if (b == 8192 + 3072) {
        float4 z = {0.f, 0.f, 0.f, 0.f};
#pragma unroll
        for (int i = 0; i < 8; i++)
            ((float4*)l)[tid * 8 + i] = z;
        return;
    }
    int tix = b - 8192;
    const int w = tix >> 10;
    tix &= 1023;
    const float* W = (w == 0) ? Wq : (w == 1) ? Wk : Wv;
    unsigned short* Wt = Wqkvt + (long)w * 1024 * 1024;
    const int bx = (tix & 31) * 32;
    const int by = (tix >> 5) * 32;
    const int tx = tid & 31;
    const int ty = (tid >> 5) * 4;
#pragma unroll
    for (int j = 0; j < 4; j++)
        t[ty + j][tx] = W[(long)(by + ty + j) * 1024 + bx + tx];
    __syncthreads();
#pragma unroll
    for (int j = 0; j < 4; j++)
        Wt[(long)(bx + ty + j) * 1024 + by + tx] = f2bf(t[tx][ty + j]);
}

extern "C" void kernel_launch(void* const* d_in, const int* in_sizes, int n_in,
                              void* d_out, int out_size, void* d_ws,
                              size_t ws_size, hipStream_t stream)
{
    const float* x  = (const float*)d_in[0];
    const float* Wq = (const float*)d_in[1];
    const float* Wk = (const float*)d_in[2];
    const float* Wv = (const float*)d_in[3];
    float* out = (float*)d_out;

    const long M1 = 1024 * 1024;
    unsigned short* u     = (unsigned short*)d_ws;
    unsigned short* xb    = u;                  // 8M
    unsigned short* Wqkvt = u + 8 * M1;         // 3M
    unsigned short* QKb   = Wqkvt + 3 * M1;     // 16M [8192 x 2048]
    unsigned short* Vtb   = QKb + 16 * M1;      // 8M  [1024 x 8192]
    unsigned short* Pb    = Vtb + 8 * M1;       // 16M [4 x 2048 x 2048]
    float* l              = (float*)(Pb + 16 * M1);  // 8192 f32

    prep<<<dim3(8192 + 3072 + 1), dim3(256), 0, stream>>>(x, Wq, Wk, Wv, xb, Wqkvt, l);

    // Q/K (blocks 0-255) + V (blocks 256-511) in one kernel
    gemm_qkv_split<<<dim3(512), dim3(512), 0, stream>>>(xb, Wqkvt, QKb, Vtb);

    // scores: C[i,j] = Q_i.K_j, exp, transposed-store to P[j][i], l[j] sums
    gemm_scores256<<<dim3(256), dim3(512), 0, stream>>>(QKb, Pb, l);

    // out = (P' @ V) / l, 128x128 tiles, 512 blocks = 1 round at 2/CU
    gemm_pv128<<<dim3(512), dim3(256), 0, stream>>>(Pb, Vtb, l, out);
}